// Round 8
// baseline (644.032 us; speedup 1.0000x reference)
//
#include <hip/hip_runtime.h>
#include <math.h>

#define N_NODES 100000
#define N_EDGES 1600000
#define HIDDEN 128

// Native 4-wide float vector — required for __builtin_nontemporal_store.
typedef float vfloat4 __attribute__((ext_vector_type(4)));

// ---------------------------------------------------------------------------
// Kernel 0: zero the du accumulator (lives inside d_out).
// ---------------------------------------------------------------------------
__global__ void zero_du_kernel(float* __restrict__ du, int n) {
    int i = blockIdx.x * blockDim.x + threadIdx.x;
    if (i < n) du[i] = 0.0f;
}

// ---------------------------------------------------------------------------
// Kernel 1: per-edge unit vector, scatter-add to both endpoints.
// unsafeAtomicAdd -> native global_atomic_add_f32 (TCC-side RMW) instead of
// the CAS retry loop plain atomicAdd(float*) lowers to without
// -munsafe-fp-atomics. Theory: R3's ~515us scatter was the CAS loop.
// ---------------------------------------------------------------------------
__global__ __launch_bounds__(256) void edge_scatter_kernel(
    const float* __restrict__ pos,
    const int* __restrict__ eidx,
    float* __restrict__ du)
{
    int e = blockIdx.x * blockDim.x + threadIdx.x;
    if (e >= N_EDGES) return;
    int r = eidx[e];
    int c = eidx[N_EDGES + e];

    float dx = pos[c * 3 + 0] - pos[r * 3 + 0];
    float dy = pos[c * 3 + 1] - pos[r * 3 + 1];
    float dz = pos[c * 3 + 2] - pos[r * 3 + 2];
    float inv = 1.0f / (sqrtf(dx * dx + dy * dy + dz * dz) + 1e-8f);
    float ux = dx * inv, uy = dy * inv, uz = dz * inv;

    unsafeAtomicAdd(&du[r * 3 + 0],  ux);
    unsafeAtomicAdd(&du[r * 3 + 1],  uy);
    unsafeAtomicAdd(&du[r * 3 + 2],  uz);
    unsafeAtomicAdd(&du[c * 3 + 0], -ux);
    unsafeAtomicAdd(&du[c * 3 + 1], -uy);
    unsafeAtomicAdd(&du[c * 3 + 2], -uz);
}

// ---------------------------------------------------------------------------
// Kernel 2: angular_info[n][:] = ||du[n]||^2, 32 lanes per node.
// ---------------------------------------------------------------------------
__global__ void angular_kernel(const float* __restrict__ du,
                               float* __restrict__ ang) {
    int gid = blockIdx.x * blockDim.x + threadIdx.x;
    int node = gid >> 5;
    int c4   = gid & 31;
    float x = du[node * 3 + 0];
    float y = du[node * 3 + 1];
    float z = du[node * 3 + 2];
    float a = x * x + y * y + z * z;
    vfloat4 v4 = {a, a, a, a};
    __builtin_nontemporal_store(v4,
        reinterpret_cast<vfloat4*>(ang + (size_t)node * HIDDEN) + c4);
}

// ---------------------------------------------------------------------------
// Kernel 3: fused per-edge dihedral scalar -> broadcast 128-wide row.
// (R6's best-performing dihedral structure, unchanged.)
// ---------------------------------------------------------------------------
__global__ __launch_bounds__(256) void dihedral_kernel(
    const float* __restrict__ pos,
    const int* __restrict__ eidx,
    const float* __restrict__ du,
    float* __restrict__ dih)
{
    __shared__ float vals[256];
    const int e0 = blockIdx.x * 256;
    const int e  = e0 + threadIdx.x;

    {
        int r = eidx[e];
        int c = eidx[N_EDGES + e];

        float dx = pos[c * 3 + 0] - pos[r * 3 + 0];
        float dy = pos[c * 3 + 1] - pos[r * 3 + 1];
        float dz = pos[c * 3 + 2] - pos[r * 3 + 2];
        float dist = sqrtf(dx * dx + dy * dy + dz * dz) + 1e-8f;
        float inv = 1.0f / dist;
        float ux = dx * inv, uy = dy * inv, uz = dz * inv;

        float vix = du[r * 3 + 0], viy = du[r * 3 + 1], viz = du[r * 3 + 2];
        float vjx = du[c * 3 + 0], vjy = du[c * 3 + 1], vjz = du[c * 3 + 2];

        float dvi = vix * ux + viy * uy + viz * uz;
        float dvj = -(vjx * ux + vjy * uy + vjz * uz);

        float wix = vix - dvi * ux;
        float wiy = viy - dvi * uy;
        float wiz = viz - dvi * uz;
        float wjx = vjx + dvj * ux;
        float wjy = vjy + dvj * uy;
        float wjz = vjz + dvj * uz;

        vals[threadIdx.x] = wix * wjx + wiy * wjy + wiz * wjz;
    }
    __syncthreads();

    vfloat4* out = reinterpret_cast<vfloat4*>(dih + (size_t)e0 * HIDDEN);
    #pragma unroll
    for (int it = 0; it < 32; ++it) {
        int i = it * 256 + threadIdx.x;   // 0 .. 8191
        float v = vals[i >> 5];
        vfloat4 v4 = {v, v, v, v};
        __builtin_nontemporal_store(v4, out + i);
    }
}

// ---------------------------------------------------------------------------
extern "C" void kernel_launch(void* const* d_in, const int* in_sizes, int n_in,
                              void* d_out, int out_size, void* d_ws, size_t ws_size,
                              hipStream_t stream) {
    const float* pos  = (const float*)d_in[0];
    const int*   eidx = (const int*)d_in[1];

    float* out = (float*)d_out;
    float* ang = out;                                         // (N, 128)
    float* dih = out + (size_t)N_NODES * HIDDEN;              // (E, 128)
    float* du  = dih + (size_t)N_EDGES * HIDDEN;              // (N, 3)

    zero_du_kernel<<<(N_NODES * 3 + 255) / 256, 256, 0, stream>>>(du, N_NODES * 3);

    edge_scatter_kernel<<<(N_EDGES + 255) / 256, 256, 0, stream>>>(pos, eidx, du);

    angular_kernel<<<(N_NODES * 32) / 256, 256, 0, stream>>>(du, ang);

    dihedral_kernel<<<N_EDGES / 256, 256, 0, stream>>>(pos, eidx, du, dih);
}

// Round 9
// 217.756 us; speedup vs baseline: 2.9576x; 2.9576x over previous
//
#include <hip/hip_runtime.h>
#include <math.h>

#define N_NODES 100000
#define N_EDGES 1600000
#define HIDDEN 128

// ---- binning geometry ------------------------------------------------------
#define NBINS      256
#define BIN_NODES  391        // 256*391 = 100096 >= 100000
#define BIN_CAP    16256      // records/bin: mean 12512, sigma ~112 -> +33s
#define CUR_STRIDE 32         // cursors padded to 1 per 128B line
#define A_THREADS  1024
#define A_EPT      2          // edges per thread (int2-vectorized)
#define A_EPB      (A_THREADS * A_EPT)                    // 2048 edges/block
#define A_BLOCKS   ((N_EDGES + A_EPB - 1) / A_EPB)        // 782
#define B_THREADS  1024

// Fixed-point scale for LDS du accumulation: unit-vector components in
// [-1,1], degree <= ~100 -> |acc| < 100*2^22 << 2^31. Quantization 2.4e-7
// per add, ~2e-5 on du — far below the 48 absmax threshold. Integer LDS
// atomicAdd is a native single ds_add_u32 (fp32 atomicAdd on LDS lowers to
// a CAS retry loop without -munsafe-fp-atomics — the R6 phase-B suspect).
#define FP_SCALE   4194304.0f
#define FP_INV     (1.0f / 4194304.0f)

// Record layout: [26:17]=own-local node (9b), [16:0]=other node id (17b).
// Both endpoints' contributions are normalize(pos[other]-pos[own]): no sign
// bit needed, and phase B never touches eidx.

// Native 4-wide float vector — required for __builtin_nontemporal_store.
typedef float vfloat4 __attribute__((ext_vector_type(4)));

// ---------------------------------------------------------------------------
// Kernel A0: zero the padded bin cursors.
// ---------------------------------------------------------------------------
__global__ void zero_cursors_kernel(unsigned* __restrict__ cur) {
    cur[threadIdx.x * CUR_STRIDE] = 0u;
}

// ---------------------------------------------------------------------------
// Kernel A: bin edges. Each edge emits a record into bin(row) and bin(col).
// Per-block LDS counts -> one global cursor atomicAdd per (block,bin), each
// cursor on its own 128B line (no same-line RMW serialization).
// ---------------------------------------------------------------------------
__global__ __launch_bounds__(A_THREADS) void bin_edges_kernel(
    const int* __restrict__ eidx,
    unsigned* __restrict__ cursors,
    unsigned* __restrict__ region)
{
    __shared__ unsigned cnt[NBINS];
    __shared__ unsigned base[NBINS];
    if (threadIdx.x < NBINS) cnt[threadIdx.x] = 0u;
    __syncthreads();

    const int e0 = blockIdx.x * A_EPB + threadIdx.x * 2;
    const bool valid = (e0 < N_EDGES);   // N_EDGES even -> e0+1 also valid

    unsigned r[A_EPT], c[A_EPT], br[A_EPT], bc[A_EPT], orow[A_EPT], ocol[A_EPT];

    if (valid) {
        int2 rr = *reinterpret_cast<const int2*>(eidx + e0);
        int2 cc = *reinterpret_cast<const int2*>(eidx + N_EDGES + e0);
        r[0] = (unsigned)rr.x; r[1] = (unsigned)rr.y;
        c[0] = (unsigned)cc.x; c[1] = (unsigned)cc.y;
        #pragma unroll
        for (int k = 0; k < A_EPT; ++k) {
            br[k] = r[k] / BIN_NODES;
            bc[k] = c[k] / BIN_NODES;
            orow[k] = atomicAdd(&cnt[br[k]], 1u);
            ocol[k] = atomicAdd(&cnt[bc[k]], 1u);
        }
    }
    __syncthreads();

    if (threadIdx.x < NBINS)
        base[threadIdx.x] =
            atomicAdd(&cursors[threadIdx.x * CUR_STRIDE], cnt[threadIdx.x]);
    __syncthreads();

    if (valid) {
        #pragma unroll
        for (int k = 0; k < A_EPT; ++k) {
            region[br[k] * BIN_CAP + base[br[k]] + orow[k]] =
                ((r[k] - br[k] * BIN_NODES) << 17) | c[k];
            region[bc[k] * BIN_CAP + base[bc[k]] + ocol[k]] =
                ((c[k] - bc[k] * BIN_NODES) << 17) | r[k];
        }
    }
}

// ---------------------------------------------------------------------------
// Kernel B: one block per bin. Coalesced uint4 record loads; own-pos from an
// LDS stage; fixed-point int32 LDS accumulate (native ds_add); write du slice
// + fused angular rows.
// ---------------------------------------------------------------------------
__device__ __forceinline__ void proc_rec(unsigned rec,
                                         const float* __restrict__ posLDS,
                                         const float* __restrict__ pos,
                                         int* __restrict__ acc) {
    unsigned other = rec & 0x1FFFFu;
    unsigned local = rec >> 17;
    float sx = posLDS[local * 3 + 0];
    float sy = posLDS[local * 3 + 1];
    float sz = posLDS[local * 3 + 2];
    float dx = pos[other * 3 + 0] - sx;
    float dy = pos[other * 3 + 1] - sy;
    float dz = pos[other * 3 + 2] - sz;
    float inv = 1.0f / (sqrtf(dx * dx + dy * dy + dz * dz) + 1e-8f);
    atomicAdd(&acc[local * 3 + 0], __float2int_rn(dx * inv * FP_SCALE));
    atomicAdd(&acc[local * 3 + 1], __float2int_rn(dy * inv * FP_SCALE));
    atomicAdd(&acc[local * 3 + 2], __float2int_rn(dz * inv * FP_SCALE));
}

__global__ __launch_bounds__(B_THREADS) void accumulate_kernel(
    const float* __restrict__ pos,
    const unsigned* __restrict__ cursors,
    const unsigned* __restrict__ region,
    float* __restrict__ du,
    float* __restrict__ ang)
{
    __shared__ int   acc[BIN_NODES * 3];     // 4692 B
    __shared__ float posLDS[BIN_NODES * 3];  // 4692 B
    const unsigned b = blockIdx.x;
    const unsigned nodebase = b * BIN_NODES;
    const unsigned nloc = min((unsigned)BIN_NODES,
                              (unsigned)(N_NODES - nodebase));

    for (int i = threadIdx.x; i < BIN_NODES * 3; i += B_THREADS) acc[i] = 0;
    for (unsigned i = threadIdx.x; i < nloc * 3; i += B_THREADS)
        posLDS[i] = pos[(size_t)nodebase * 3 + i];
    __syncthreads();

    const unsigned n = cursors[b * CUR_STRIDE];
    const unsigned* __restrict__ reg = region + (size_t)b * BIN_CAP;
    const unsigned n4 = n & ~3u;

    for (unsigned i = threadIdx.x * 4; i < n4; i += B_THREADS * 4) {
        uint4 rc = *reinterpret_cast<const uint4*>(reg + i);
        proc_rec(rc.x, posLDS, pos, acc);
        proc_rec(rc.y, posLDS, pos, acc);
        proc_rec(rc.z, posLDS, pos, acc);
        proc_rec(rc.w, posLDS, pos, acc);
    }
    for (unsigned i = n4 + threadIdx.x; i < n; i += B_THREADS)
        proc_rec(reg[i], posLDS, pos, acc);
    __syncthreads();

    for (unsigned i = threadIdx.x; i < nloc * 3; i += B_THREADS)
        du[(size_t)nodebase * 3 + i] = (float)acc[i] * FP_INV;

    for (unsigned j = threadIdx.x; j < nloc * 32; j += B_THREADS) {
        unsigned node = j >> 5, c4 = j & 31;
        float x = (float)acc[node * 3 + 0] * FP_INV;
        float y = (float)acc[node * 3 + 1] * FP_INV;
        float z = (float)acc[node * 3 + 2] * FP_INV;
        float a = x * x + y * y + z * z;
        vfloat4 v4 = {a, a, a, a};
        __builtin_nontemporal_store(v4,
            reinterpret_cast<vfloat4*>(ang + (size_t)(nodebase + node) * HIDDEN) + c4);
    }
}

// ---------------------------------------------------------------------------
// Kernel C: fused per-edge dihedral scalar -> broadcast 128-wide row
// (R6's best-performing structure, unchanged).
// ---------------------------------------------------------------------------
__global__ __launch_bounds__(256) void dihedral_kernel(
    const float* __restrict__ pos,
    const int* __restrict__ eidx,
    const float* __restrict__ du,
    float* __restrict__ dih)
{
    __shared__ float vals[256];
    const int e0 = blockIdx.x * 256;
    const int e  = e0 + threadIdx.x;

    {
        int r = eidx[e];
        int c = eidx[N_EDGES + e];

        float dx = pos[c * 3 + 0] - pos[r * 3 + 0];
        float dy = pos[c * 3 + 1] - pos[r * 3 + 1];
        float dz = pos[c * 3 + 2] - pos[r * 3 + 2];
        float dist = sqrtf(dx * dx + dy * dy + dz * dz) + 1e-8f;
        float inv = 1.0f / dist;
        float ux = dx * inv, uy = dy * inv, uz = dz * inv;

        float vix = du[r * 3 + 0], viy = du[r * 3 + 1], viz = du[r * 3 + 2];
        float vjx = du[c * 3 + 0], vjy = du[c * 3 + 1], vjz = du[c * 3 + 2];

        float dvi = vix * ux + viy * uy + viz * uz;
        float dvj = -(vjx * ux + vjy * uy + vjz * uz);

        float wix = vix - dvi * ux;
        float wiy = viy - dvi * uy;
        float wiz = viz - dvi * uz;
        float wjx = vjx + dvj * ux;
        float wjy = vjy + dvj * uy;
        float wjz = vjz + dvj * uz;

        vals[threadIdx.x] = wix * wjx + wiy * wjy + wiz * wjz;
    }
    __syncthreads();

    vfloat4* out = reinterpret_cast<vfloat4*>(dih + (size_t)e0 * HIDDEN);
    #pragma unroll
    for (int it = 0; it < 32; ++it) {
        int i = it * 256 + threadIdx.x;   // 0 .. 8191
        float v = vals[i >> 5];
        vfloat4 v4 = {v, v, v, v};
        __builtin_nontemporal_store(v4, out + i);
    }
}

// ---------------------------------------------------------------------------
// Fallback path (ws too small): direct native-atomic scatter (R8 structure).
// ---------------------------------------------------------------------------
__global__ void zero_du_kernel(float* __restrict__ du, int n) {
    int i = blockIdx.x * blockDim.x + threadIdx.x;
    if (i < n) du[i] = 0.0f;
}

__global__ void edge_scatter_kernel(const float* __restrict__ pos,
                                    const int* __restrict__ eidx,
                                    float* __restrict__ du) {
    int e = blockIdx.x * blockDim.x + threadIdx.x;
    if (e >= N_EDGES) return;
    int r = eidx[e];
    int c = eidx[N_EDGES + e];
    float dx = pos[c * 3 + 0] - pos[r * 3 + 0];
    float dy = pos[c * 3 + 1] - pos[r * 3 + 1];
    float dz = pos[c * 3 + 2] - pos[r * 3 + 2];
    float inv = 1.0f / (sqrtf(dx * dx + dy * dy + dz * dz) + 1e-8f);
    float ux = dx * inv, uy = dy * inv, uz = dz * inv;
    unsafeAtomicAdd(&du[r * 3 + 0],  ux);
    unsafeAtomicAdd(&du[r * 3 + 1],  uy);
    unsafeAtomicAdd(&du[r * 3 + 2],  uz);
    unsafeAtomicAdd(&du[c * 3 + 0], -ux);
    unsafeAtomicAdd(&du[c * 3 + 1], -uy);
    unsafeAtomicAdd(&du[c * 3 + 2], -uz);
}

__global__ void angular_kernel(const float* __restrict__ du,
                               float* __restrict__ ang) {
    int gid = blockIdx.x * blockDim.x + threadIdx.x;
    int node = gid >> 5;
    int c4   = gid & 31;
    float x = du[node * 3 + 0];
    float y = du[node * 3 + 1];
    float z = du[node * 3 + 2];
    float a = x * x + y * y + z * z;
    vfloat4 v4 = {a, a, a, a};
    __builtin_nontemporal_store(v4,
        reinterpret_cast<vfloat4*>(ang + (size_t)node * HIDDEN) + c4);
}

// ---------------------------------------------------------------------------
extern "C" void kernel_launch(void* const* d_in, const int* in_sizes, int n_in,
                              void* d_out, int out_size, void* d_ws, size_t ws_size,
                              hipStream_t stream) {
    const float* pos  = (const float*)d_in[0];
    const int*   eidx = (const int*)d_in[1];

    float* out = (float*)d_out;
    float* ang = out;                                         // (N, 128)
    float* dih = out + (size_t)N_NODES * HIDDEN;              // (E, 128)
    float* du  = dih + (size_t)N_EDGES * HIDDEN;              // (N, 3)

    const size_t curBytes = (size_t)NBINS * CUR_STRIDE * sizeof(unsigned); // 32KB
    const size_t need = curBytes + (size_t)NBINS * BIN_CAP * sizeof(unsigned);

    if (ws_size >= need) {
        unsigned* cursors = (unsigned*)d_ws;                      // padded
        unsigned* region  = (unsigned*)d_ws + NBINS * CUR_STRIDE; // bin regions

        zero_cursors_kernel<<<1, NBINS, 0, stream>>>(cursors);
        bin_edges_kernel<<<A_BLOCKS, A_THREADS, 0, stream>>>(eidx, cursors, region);
        accumulate_kernel<<<NBINS, B_THREADS, 0, stream>>>(pos, cursors,
                                                           region, du, ang);
    } else {
        zero_du_kernel<<<(N_NODES * 3 + 255) / 256, 256, 0, stream>>>(du, N_NODES * 3);
        edge_scatter_kernel<<<(N_EDGES + 255) / 256, 256, 0, stream>>>(pos, eidx, du);
        angular_kernel<<<(N_NODES * 32) / 256, 256, 0, stream>>>(du, ang);
    }

    dihedral_kernel<<<N_EDGES / 256, 256, 0, stream>>>(pos, eidx, du, dih);
}

// Round 10
// 213.608 us; speedup vs baseline: 3.0150x; 1.0194x over previous
//
#include <hip/hip_runtime.h>
#include <math.h>

#define N_NODES 100000
#define N_EDGES 1600000
#define HIDDEN 128

// ---- binning geometry ------------------------------------------------------
#define NBINS      256
#define BIN_NODES  391        // 256*391 = 100096 >= 100000
#define BIN_CAP    14336      // mean 12500, sigma ~112 -> +16s; 14*1024
#define CUR_STRIDE 32         // cursors padded to 1 per 128B line
#define A_THREADS  1024
#define A_EPT      8          // edges per thread (int2-vectorized, 4 pairs)
#define A_EPB      (A_THREADS * A_EPT)                    // 8192 edges/block
#define A_BLOCKS   ((N_EDGES + A_EPB - 1) / A_EPB)        // 196
#define B_THREADS  1024

// Fixed-point scale for LDS du accumulation (native ds_add_u32; fp32 LDS
// atomicAdd lowers to a CAS retry loop). Quantization ~2e-5 << threshold 48.
#define FP_SCALE   4194304.0f
#define FP_INV     (1.0f / 4194304.0f)

// Record layout: [26:17]=own-local node (9b), [16:0]=other node id (17b).
// Both endpoints' contributions are normalize(pos[other]-pos[own]).

typedef float vfloat4 __attribute__((ext_vector_type(4)));

// ---------------------------------------------------------------------------
// Kernel P: prep — zero padded cursors AND build pos4[n] = (x,y,z,0).
// float4 gathers in B become one dwordx4 instead of 3 scalar dwords.
// ---------------------------------------------------------------------------
__global__ __launch_bounds__(256) void prep_kernel(
    const float* __restrict__ pos,
    unsigned* __restrict__ cursors,
    float4* __restrict__ pos4)
{
    int gid = blockIdx.x * 256 + threadIdx.x;
    if (gid < NBINS) cursors[gid * CUR_STRIDE] = 0u;
    if (gid < N_NODES) {
        pos4[gid] = make_float4(pos[gid * 3 + 0], pos[gid * 3 + 1],
                                pos[gid * 3 + 2], 0.0f);
    }
}

// ---------------------------------------------------------------------------
// Kernel A: bin edges, 8 edges/thread. Per-block LDS counts -> one padded
// global cursor atomicAdd per (block,bin) -> 64-record (256B) contiguous
// runs per (block,bin): full-line scattered stores, 50K cursor atomics.
// ---------------------------------------------------------------------------
__global__ __launch_bounds__(A_THREADS) void bin_edges_kernel(
    const int* __restrict__ eidx,
    unsigned* __restrict__ cursors,
    unsigned* __restrict__ region)
{
    __shared__ unsigned cnt[NBINS];
    __shared__ unsigned base[NBINS];
    if (threadIdx.x < NBINS) cnt[threadIdx.x] = 0u;
    __syncthreads();

    const int eb = blockIdx.x * A_EPB + threadIdx.x * 2;

    bool     val[A_EPT];
    unsigned r[A_EPT], c[A_EPT], br[A_EPT], bc[A_EPT], orow[A_EPT], ocol[A_EPT];

    #pragma unroll
    for (int k = 0; k < A_EPT; k += 2) {
        int e = eb + k * A_THREADS;          // N_EDGES even -> e,e+1 together
        bool v = (e < N_EDGES);
        val[k] = v; val[k + 1] = v;
        if (v) {
            int2 rr = *reinterpret_cast<const int2*>(eidx + e);
            int2 cc = *reinterpret_cast<const int2*>(eidx + N_EDGES + e);
            r[k] = (unsigned)rr.x; r[k + 1] = (unsigned)rr.y;
            c[k] = (unsigned)cc.x; c[k + 1] = (unsigned)cc.y;
        }
    }
    #pragma unroll
    for (int k = 0; k < A_EPT; ++k) {
        if (val[k]) {
            br[k] = r[k] / BIN_NODES;
            bc[k] = c[k] / BIN_NODES;
            orow[k] = atomicAdd(&cnt[br[k]], 1u);
            ocol[k] = atomicAdd(&cnt[bc[k]], 1u);
        }
    }
    __syncthreads();

    if (threadIdx.x < NBINS)
        base[threadIdx.x] =
            atomicAdd(&cursors[threadIdx.x * CUR_STRIDE], cnt[threadIdx.x]);
    __syncthreads();

    #pragma unroll
    for (int k = 0; k < A_EPT; ++k) {
        if (val[k]) {
            region[br[k] * BIN_CAP + base[br[k]] + orow[k]] =
                ((r[k] - br[k] * BIN_NODES) << 17) | c[k];
            region[bc[k] * BIN_CAP + base[bc[k]] + ocol[k]] =
                ((c[k] - bc[k] * BIN_NODES) << 17) | r[k];
        }
    }
}

// ---------------------------------------------------------------------------
// Kernel B: one block per bin. uint4 record loads; own-pos via ds_read_b128,
// other-pos via one dwordx4 gather; int32 fixed-point LDS accumulate; write
// du slice + fused angular rows.
// ---------------------------------------------------------------------------
__device__ __forceinline__ void proc_rec(unsigned rec,
                                         const float4* __restrict__ posLDS4,
                                         const float4* __restrict__ pos4,
                                         int* __restrict__ acc) {
    unsigned other = rec & 0x1FFFFu;
    unsigned local = rec >> 17;
    float4 s = posLDS4[local];
    float4 p = pos4[other];
    float dx = p.x - s.x;
    float dy = p.y - s.y;
    float dz = p.z - s.z;
    float inv = 1.0f / (sqrtf(dx * dx + dy * dy + dz * dz) + 1e-8f);
    atomicAdd(&acc[local * 3 + 0], __float2int_rn(dx * inv * FP_SCALE));
    atomicAdd(&acc[local * 3 + 1], __float2int_rn(dy * inv * FP_SCALE));
    atomicAdd(&acc[local * 3 + 2], __float2int_rn(dz * inv * FP_SCALE));
}

__global__ __launch_bounds__(B_THREADS) void accumulate_kernel(
    const float4* __restrict__ pos4,
    const unsigned* __restrict__ cursors,
    const unsigned* __restrict__ region,
    float* __restrict__ du,
    float* __restrict__ ang)
{
    __shared__ int    acc[BIN_NODES * 3];      // 4692 B
    __shared__ float4 posLDS4[BIN_NODES];      // 6256 B
    const unsigned b = blockIdx.x;
    const unsigned nodebase = b * BIN_NODES;
    const unsigned nloc = min((unsigned)BIN_NODES,
                              (unsigned)(N_NODES - nodebase));

    for (int i = threadIdx.x; i < BIN_NODES * 3; i += B_THREADS) acc[i] = 0;
    for (unsigned i = threadIdx.x; i < nloc; i += B_THREADS)
        posLDS4[i] = pos4[nodebase + i];
    __syncthreads();

    const unsigned n = cursors[b * CUR_STRIDE];
    const unsigned* __restrict__ reg = region + (size_t)b * BIN_CAP;
    const unsigned n4 = n & ~3u;

    for (unsigned i = threadIdx.x * 4; i < n4; i += B_THREADS * 4) {
        uint4 rc = *reinterpret_cast<const uint4*>(reg + i);
        proc_rec(rc.x, posLDS4, pos4, acc);
        proc_rec(rc.y, posLDS4, pos4, acc);
        proc_rec(rc.z, posLDS4, pos4, acc);
        proc_rec(rc.w, posLDS4, pos4, acc);
    }
    for (unsigned i = n4 + threadIdx.x; i < n; i += B_THREADS)
        proc_rec(reg[i], posLDS4, pos4, acc);
    __syncthreads();

    for (unsigned i = threadIdx.x; i < nloc * 3; i += B_THREADS)
        du[(size_t)nodebase * 3 + i] = (float)acc[i] * FP_INV;

    for (unsigned j = threadIdx.x; j < nloc * 32; j += B_THREADS) {
        unsigned node = j >> 5, c4 = j & 31;
        float x = (float)acc[node * 3 + 0] * FP_INV;
        float y = (float)acc[node * 3 + 1] * FP_INV;
        float z = (float)acc[node * 3 + 2] * FP_INV;
        float a = x * x + y * y + z * z;
        vfloat4 v4 = {a, a, a, a};
        __builtin_nontemporal_store(v4,
            reinterpret_cast<vfloat4*>(ang + (size_t)(nodebase + node) * HIDDEN) + c4);
    }
}

// ---------------------------------------------------------------------------
// Kernel C: fused per-edge dihedral scalar -> broadcast 128-wide row
// (unchanged — inferred ~138us vs ~125us pure-fill floor).
// ---------------------------------------------------------------------------
__global__ __launch_bounds__(256) void dihedral_kernel(
    const float* __restrict__ pos,
    const int* __restrict__ eidx,
    const float* __restrict__ du,
    float* __restrict__ dih)
{
    __shared__ float vals[256];
    const int e0 = blockIdx.x * 256;
    const int e  = e0 + threadIdx.x;

    {
        int r = eidx[e];
        int c = eidx[N_EDGES + e];

        float dx = pos[c * 3 + 0] - pos[r * 3 + 0];
        float dy = pos[c * 3 + 1] - pos[r * 3 + 1];
        float dz = pos[c * 3 + 2] - pos[r * 3 + 2];
        float dist = sqrtf(dx * dx + dy * dy + dz * dz) + 1e-8f;
        float inv = 1.0f / dist;
        float ux = dx * inv, uy = dy * inv, uz = dz * inv;

        float vix = du[r * 3 + 0], viy = du[r * 3 + 1], viz = du[r * 3 + 2];
        float vjx = du[c * 3 + 0], vjy = du[c * 3 + 1], vjz = du[c * 3 + 2];

        float dvi = vix * ux + viy * uy + viz * uz;
        float dvj = -(vjx * ux + vjy * uy + vjz * uz);

        float wix = vix - dvi * ux;
        float wiy = viy - dvi * uy;
        float wiz = viz - dvi * uz;
        float wjx = vjx + dvj * ux;
        float wjy = vjy + dvj * uy;
        float wjz = vjz + dvj * uz;

        vals[threadIdx.x] = wix * wjx + wiy * wjy + wiz * wjz;
    }
    __syncthreads();

    vfloat4* out = reinterpret_cast<vfloat4*>(dih + (size_t)e0 * HIDDEN);
    #pragma unroll
    for (int it = 0; it < 32; ++it) {
        int i = it * 256 + threadIdx.x;   // 0 .. 8191
        float v = vals[i >> 5];
        vfloat4 v4 = {v, v, v, v};
        __builtin_nontemporal_store(v4, out + i);
    }
}

// ---------------------------------------------------------------------------
// Fallback path (ws too small): direct native-atomic scatter.
// ---------------------------------------------------------------------------
__global__ void zero_du_kernel(float* __restrict__ du, int n) {
    int i = blockIdx.x * blockDim.x + threadIdx.x;
    if (i < n) du[i] = 0.0f;
}

__global__ void edge_scatter_kernel(const float* __restrict__ pos,
                                    const int* __restrict__ eidx,
                                    float* __restrict__ du) {
    int e = blockIdx.x * blockDim.x + threadIdx.x;
    if (e >= N_EDGES) return;
    int r = eidx[e];
    int c = eidx[N_EDGES + e];
    float dx = pos[c * 3 + 0] - pos[r * 3 + 0];
    float dy = pos[c * 3 + 1] - pos[r * 3 + 1];
    float dz = pos[c * 3 + 2] - pos[r * 3 + 2];
    float inv = 1.0f / (sqrtf(dx * dx + dy * dy + dz * dz) + 1e-8f);
    float ux = dx * inv, uy = dy * inv, uz = dz * inv;
    unsafeAtomicAdd(&du[r * 3 + 0],  ux);
    unsafeAtomicAdd(&du[r * 3 + 1],  uy);
    unsafeAtomicAdd(&du[r * 3 + 2],  uz);
    unsafeAtomicAdd(&du[c * 3 + 0], -ux);
    unsafeAtomicAdd(&du[c * 3 + 1], -uy);
    unsafeAtomicAdd(&du[c * 3 + 2], -uz);
}

__global__ void angular_kernel(const float* __restrict__ du,
                               float* __restrict__ ang) {
    int gid = blockIdx.x * blockDim.x + threadIdx.x;
    int node = gid >> 5;
    int c4   = gid & 31;
    float x = du[node * 3 + 0];
    float y = du[node * 3 + 1];
    float z = du[node * 3 + 2];
    float a = x * x + y * y + z * z;
    vfloat4 v4 = {a, a, a, a};
    __builtin_nontemporal_store(v4,
        reinterpret_cast<vfloat4*>(ang + (size_t)node * HIDDEN) + c4);
}

// ---------------------------------------------------------------------------
extern "C" void kernel_launch(void* const* d_in, const int* in_sizes, int n_in,
                              void* d_out, int out_size, void* d_ws, size_t ws_size,
                              hipStream_t stream) {
    const float* pos  = (const float*)d_in[0];
    const int*   eidx = (const int*)d_in[1];

    float* out = (float*)d_out;
    float* ang = out;                                         // (N, 128)
    float* dih = out + (size_t)N_NODES * HIDDEN;              // (E, 128)
    float* du  = dih + (size_t)N_EDGES * HIDDEN;              // (N, 3)

    const size_t curWords = (size_t)NBINS * CUR_STRIDE;                  // 32KB
    const size_t regWords = (size_t)NBINS * BIN_CAP;                     // 14.7MB
    const size_t need = (curWords + regWords) * sizeof(unsigned)
                      + (size_t)(N_NODES + 64) * sizeof(float4);         // ~16.4MB

    if (ws_size >= need) {
        unsigned* cursors = (unsigned*)d_ws;
        unsigned* region  = cursors + curWords;
        float4*   pos4    = (float4*)(region + regWords);

        prep_kernel<<<(N_NODES + 255) / 256, 256, 0, stream>>>(pos, cursors, pos4);
        bin_edges_kernel<<<A_BLOCKS, A_THREADS, 0, stream>>>(eidx, cursors, region);
        accumulate_kernel<<<NBINS, B_THREADS, 0, stream>>>(pos4, cursors,
                                                           region, du, ang);
    } else {
        zero_du_kernel<<<(N_NODES * 3 + 255) / 256, 256, 0, stream>>>(du, N_NODES * 3);
        edge_scatter_kernel<<<(N_EDGES + 255) / 256, 256, 0, stream>>>(pos, eidx, du);
        angular_kernel<<<(N_NODES * 32) / 256, 256, 0, stream>>>(du, ang);
    }

    dihedral_kernel<<<N_EDGES / 256, 256, 0, stream>>>(pos, eidx, du, dih);
}

// Round 11
// 212.080 us; speedup vs baseline: 3.0367x; 1.0072x over previous
//
#include <hip/hip_runtime.h>
#include <math.h>

#define N_NODES 100000
#define N_EDGES 1600000
#define HIDDEN 128

// ---- binning geometry ------------------------------------------------------
#define NBINS      256
#define BIN_NODES  391        // 256*391 = 100096 >= 100000
#define BIN_CAP_MAX 14336     // preferred cap (+16 sigma); runtime-shrinks
#define BIN_CAP_MIN 13056     // +4.9 sigma — below this, fall back
#define CUR_STRIDE 32         // cursors padded to 1 per 128B line
#define A_THREADS  1024
#define A_EPT      8
#define A_EPB      (A_THREADS * A_EPT)                    // 8192 edges/block
#define A_BLOCKS   ((N_EDGES + A_EPB - 1) / A_EPB)        // 196
#define B_THREADS  1024
#define NPAD       100096     // N_NODES rounded up (table sizing)

// Fixed-point scale for LDS du accumulation (native ds_add_u32).
#define FP_SCALE   4194304.0f
#define FP_INV     (1.0f / 4194304.0f)

// Record layout: [26:17]=own-local node (9b), [16:0]=other node id (17b).

typedef float vfloat4 __attribute__((ext_vector_type(4)));

// ---------------------------------------------------------------------------
// Kernel P: prep — zero padded cursors AND build pos4[n] = (x,y,z,0).
// ---------------------------------------------------------------------------
__global__ __launch_bounds__(256) void prep_kernel(
    const float* __restrict__ pos,
    unsigned* __restrict__ cursors,
    float4* __restrict__ pos4)
{
    int gid = blockIdx.x * 256 + threadIdx.x;
    if (gid < NBINS) cursors[gid * CUR_STRIDE] = 0u;
    if (gid < N_NODES) {
        pos4[gid] = make_float4(pos[gid * 3 + 0], pos[gid * 3 + 1],
                                pos[gid * 3 + 2], 0.0f);
    }
}

// ---------------------------------------------------------------------------
// Kernel A: bin edges, 8 edges/thread, runtime bin capacity.
// ---------------------------------------------------------------------------
__global__ __launch_bounds__(A_THREADS) void bin_edges_kernel(
    const int* __restrict__ eidx,
    unsigned* __restrict__ cursors,
    unsigned* __restrict__ region,
    int cap)
{
    __shared__ unsigned cnt[NBINS];
    __shared__ unsigned base[NBINS];
    if (threadIdx.x < NBINS) cnt[threadIdx.x] = 0u;
    __syncthreads();

    const int eb = blockIdx.x * A_EPB + threadIdx.x * 2;

    bool     val[A_EPT];
    unsigned r[A_EPT], c[A_EPT], br[A_EPT], bc[A_EPT], orow[A_EPT], ocol[A_EPT];

    #pragma unroll
    for (int k = 0; k < A_EPT; k += 2) {
        int e = eb + k * A_THREADS;
        bool v = (e < N_EDGES);
        val[k] = v; val[k + 1] = v;
        if (v) {
            int2 rr = *reinterpret_cast<const int2*>(eidx + e);
            int2 cc = *reinterpret_cast<const int2*>(eidx + N_EDGES + e);
            r[k] = (unsigned)rr.x; r[k + 1] = (unsigned)rr.y;
            c[k] = (unsigned)cc.x; c[k + 1] = (unsigned)cc.y;
        }
    }
    #pragma unroll
    for (int k = 0; k < A_EPT; ++k) {
        if (val[k]) {
            br[k] = r[k] / BIN_NODES;
            bc[k] = c[k] / BIN_NODES;
            orow[k] = atomicAdd(&cnt[br[k]], 1u);
            ocol[k] = atomicAdd(&cnt[bc[k]], 1u);
        }
    }
    __syncthreads();

    if (threadIdx.x < NBINS)
        base[threadIdx.x] =
            atomicAdd(&cursors[threadIdx.x * CUR_STRIDE], cnt[threadIdx.x]);
    __syncthreads();

    #pragma unroll
    for (int k = 0; k < A_EPT; ++k) {
        if (val[k]) {
            region[(size_t)br[k] * cap + base[br[k]] + orow[k]] =
                ((r[k] - br[k] * BIN_NODES) << 17) | c[k];
            region[(size_t)bc[k] * cap + base[bc[k]] + ocol[k]] =
                ((c[k] - bc[k] * BIN_NODES) << 17) | r[k];
        }
    }
}

// ---------------------------------------------------------------------------
// Kernel B: one block per bin; int32 fixed-point LDS accumulate; writes the
// du slice, fused angular rows, AND du4[n]=(du.xyz, ||du||^2) for kernel C.
// ---------------------------------------------------------------------------
__device__ __forceinline__ void proc_rec(unsigned rec,
                                         const float4* __restrict__ posLDS4,
                                         const float4* __restrict__ pos4,
                                         int* __restrict__ acc) {
    unsigned other = rec & 0x1FFFFu;
    unsigned local = rec >> 17;
    float4 s = posLDS4[local];
    float4 p = pos4[other];
    float dx = p.x - s.x;
    float dy = p.y - s.y;
    float dz = p.z - s.z;
    float inv = 1.0f / (sqrtf(dx * dx + dy * dy + dz * dz) + 1e-8f);
    atomicAdd(&acc[local * 3 + 0], __float2int_rn(dx * inv * FP_SCALE));
    atomicAdd(&acc[local * 3 + 1], __float2int_rn(dy * inv * FP_SCALE));
    atomicAdd(&acc[local * 3 + 2], __float2int_rn(dz * inv * FP_SCALE));
}

__global__ __launch_bounds__(B_THREADS) void accumulate_kernel(
    const float4* __restrict__ pos4,
    const unsigned* __restrict__ cursors,
    const unsigned* __restrict__ region,
    int cap,
    float* __restrict__ du,
    float* __restrict__ ang,
    float4* __restrict__ du4)
{
    __shared__ int    acc[BIN_NODES * 3];      // 4692 B
    __shared__ float4 posLDS4[BIN_NODES];      // 6256 B
    const unsigned b = blockIdx.x;
    const unsigned nodebase = b * BIN_NODES;
    const unsigned nloc = min((unsigned)BIN_NODES,
                              (unsigned)(N_NODES - nodebase));

    for (int i = threadIdx.x; i < BIN_NODES * 3; i += B_THREADS) acc[i] = 0;
    for (unsigned i = threadIdx.x; i < nloc; i += B_THREADS)
        posLDS4[i] = pos4[nodebase + i];
    __syncthreads();

    const unsigned n = cursors[b * CUR_STRIDE];
    const unsigned* __restrict__ reg = region + (size_t)b * cap;
    const unsigned n4 = n & ~3u;

    for (unsigned i = threadIdx.x * 4; i < n4; i += B_THREADS * 4) {
        uint4 rc = *reinterpret_cast<const uint4*>(reg + i);
        proc_rec(rc.x, posLDS4, pos4, acc);
        proc_rec(rc.y, posLDS4, pos4, acc);
        proc_rec(rc.z, posLDS4, pos4, acc);
        proc_rec(rc.w, posLDS4, pos4, acc);
    }
    for (unsigned i = n4 + threadIdx.x; i < n; i += B_THREADS)
        proc_rec(reg[i], posLDS4, pos4, acc);
    __syncthreads();

    for (unsigned i = threadIdx.x; i < nloc * 3; i += B_THREADS)
        du[(size_t)nodebase * 3 + i] = (float)acc[i] * FP_INV;

    for (unsigned i = threadIdx.x; i < nloc; i += B_THREADS) {
        float x = (float)acc[i * 3 + 0] * FP_INV;
        float y = (float)acc[i * 3 + 1] * FP_INV;
        float z = (float)acc[i * 3 + 2] * FP_INV;
        du4[nodebase + i] = make_float4(x, y, z, x * x + y * y + z * z);
    }

    for (unsigned j = threadIdx.x; j < nloc * 32; j += B_THREADS) {
        unsigned node = j >> 5, c4 = j & 31;
        float x = (float)acc[node * 3 + 0] * FP_INV;
        float y = (float)acc[node * 3 + 1] * FP_INV;
        float z = (float)acc[node * 3 + 2] * FP_INV;
        float a = x * x + y * y + z * z;
        vfloat4 v4 = {a, a, a, a};
        __builtin_nontemporal_store(v4,
            reinterpret_cast<vfloat4*>(ang + (size_t)(nodebase + node) * HIDDEN) + c4);
    }
}

// ---------------------------------------------------------------------------
// Kernel C: dihedral via pos4/du4 vector gathers (4 dwordx4/thread instead of
// 12 scalar). Exact algebra: w_ij . w_ji = v_i.v_j - (v_i.u)(v_j.u)(2 - u.u).
// ---------------------------------------------------------------------------
__global__ __launch_bounds__(256) void dihedral_kernel(
    const float4* __restrict__ pos4,
    const float4* __restrict__ du4,
    const int* __restrict__ eidx,
    float* __restrict__ dih)
{
    __shared__ float vals[256];
    const int e0 = blockIdx.x * 256;
    const int e  = e0 + threadIdx.x;

    {
        int r = eidx[e];
        int c = eidx[N_EDGES + e];
        float4 pr = pos4[r];
        float4 pc = pos4[c];
        float4 vi = du4[r];
        float4 vj = du4[c];

        float dx = pc.x - pr.x, dy = pc.y - pr.y, dz = pc.z - pr.z;
        float inv = 1.0f / (sqrtf(dx * dx + dy * dy + dz * dz) + 1e-8f);
        float ux = dx * inv, uy = dy * inv, uz = dz * inv;

        float a  = vi.x * ux + vi.y * uy + vi.z * uz;   // v_i . u
        float b  = vj.x * ux + vj.y * uy + vj.z * uz;   // v_j . u
        float vv = vi.x * vj.x + vi.y * vj.y + vi.z * vj.z;
        float uu = ux * ux + uy * uy + uz * uz;

        vals[threadIdx.x] = vv - a * b * (2.0f - uu);
    }
    __syncthreads();

    vfloat4* out = reinterpret_cast<vfloat4*>(dih + (size_t)e0 * HIDDEN);
    #pragma unroll
    for (int it = 0; it < 32; ++it) {
        int i = it * 256 + threadIdx.x;   // 0 .. 8191
        float v = vals[i >> 5];
        vfloat4 v4 = {v, v, v, v};
        __builtin_nontemporal_store(v4, out + i);
    }
}

// ---------------------------------------------------------------------------
// Fallback path (ws too small): direct native-atomic scatter + fused dihedral.
// ---------------------------------------------------------------------------
__global__ void zero_du_kernel(float* __restrict__ du, int n) {
    int i = blockIdx.x * blockDim.x + threadIdx.x;
    if (i < n) du[i] = 0.0f;
}

__global__ void edge_scatter_kernel(const float* __restrict__ pos,
                                    const int* __restrict__ eidx,
                                    float* __restrict__ du) {
    int e = blockIdx.x * blockDim.x + threadIdx.x;
    if (e >= N_EDGES) return;
    int r = eidx[e];
    int c = eidx[N_EDGES + e];
    float dx = pos[c * 3 + 0] - pos[r * 3 + 0];
    float dy = pos[c * 3 + 1] - pos[r * 3 + 1];
    float dz = pos[c * 3 + 2] - pos[r * 3 + 2];
    float inv = 1.0f / (sqrtf(dx * dx + dy * dy + dz * dz) + 1e-8f);
    float ux = dx * inv, uy = dy * inv, uz = dz * inv;
    unsafeAtomicAdd(&du[r * 3 + 0],  ux);
    unsafeAtomicAdd(&du[r * 3 + 1],  uy);
    unsafeAtomicAdd(&du[r * 3 + 2],  uz);
    unsafeAtomicAdd(&du[c * 3 + 0], -ux);
    unsafeAtomicAdd(&du[c * 3 + 1], -uy);
    unsafeAtomicAdd(&du[c * 3 + 2], -uz);
}

__global__ void angular_kernel(const float* __restrict__ du,
                               float* __restrict__ ang) {
    int gid = blockIdx.x * blockDim.x + threadIdx.x;
    int node = gid >> 5;
    int c4   = gid & 31;
    float x = du[node * 3 + 0];
    float y = du[node * 3 + 1];
    float z = du[node * 3 + 2];
    float a = x * x + y * y + z * z;
    vfloat4 v4 = {a, a, a, a};
    __builtin_nontemporal_store(v4,
        reinterpret_cast<vfloat4*>(ang + (size_t)node * HIDDEN) + c4);
}

__global__ __launch_bounds__(256) void dihedral_fallback_kernel(
    const float* __restrict__ pos,
    const int* __restrict__ eidx,
    const float* __restrict__ du,
    float* __restrict__ dih)
{
    __shared__ float vals[256];
    const int e0 = blockIdx.x * 256;
    const int e  = e0 + threadIdx.x;
    {
        int r = eidx[e];
        int c = eidx[N_EDGES + e];
        float dx = pos[c * 3 + 0] - pos[r * 3 + 0];
        float dy = pos[c * 3 + 1] - pos[r * 3 + 1];
        float dz = pos[c * 3 + 2] - pos[r * 3 + 2];
        float inv = 1.0f / (sqrtf(dx * dx + dy * dy + dz * dz) + 1e-8f);
        float ux = dx * inv, uy = dy * inv, uz = dz * inv;
        float vix = du[r * 3 + 0], viy = du[r * 3 + 1], viz = du[r * 3 + 2];
        float vjx = du[c * 3 + 0], vjy = du[c * 3 + 1], vjz = du[c * 3 + 2];
        float dvi = vix * ux + viy * uy + viz * uz;
        float dvj = -(vjx * ux + vjy * uy + vjz * uz);
        float wix = vix - dvi * ux, wiy = viy - dvi * uy, wiz = viz - dvi * uz;
        float wjx = vjx + dvj * ux, wjy = vjy + dvj * uy, wjz = vjz + dvj * uz;
        vals[threadIdx.x] = wix * wjx + wiy * wjy + wiz * wjz;
    }
    __syncthreads();
    vfloat4* out = reinterpret_cast<vfloat4*>(dih + (size_t)e0 * HIDDEN);
    #pragma unroll
    for (int it = 0; it < 32; ++it) {
        int i = it * 256 + threadIdx.x;
        float v = vals[i >> 5];
        vfloat4 v4 = {v, v, v, v};
        __builtin_nontemporal_store(v4, out + i);
    }
}

// ---------------------------------------------------------------------------
extern "C" void kernel_launch(void* const* d_in, const int* in_sizes, int n_in,
                              void* d_out, int out_size, void* d_ws, size_t ws_size,
                              hipStream_t stream) {
    const float* pos  = (const float*)d_in[0];
    const int*   eidx = (const int*)d_in[1];

    float* out = (float*)d_out;
    float* ang = out;                                         // (N, 128)
    float* dih = out + (size_t)N_NODES * HIDDEN;              // (E, 128)
    float* du  = dih + (size_t)N_EDGES * HIDDEN;              // (N, 3)

    // ws layout: cursors | pos4 | du4 | region (runtime-capped bins)
    const size_t curWords  = (size_t)NBINS * CUR_STRIDE;   // 8192
    const size_t tblWords  = (size_t)NPAD * 4;             // 400384 each
    const size_t wsWords   = ws_size / 4;

    int cap = 0;
    if (wsWords > curWords + 2 * tblWords) {
        size_t avail = (wsWords - curWords - 2 * tblWords) / NBINS;
        avail &= ~(size_t)255;                             // keep 16B alignment
        cap = (int)(avail < BIN_CAP_MAX ? avail : BIN_CAP_MAX);
    }

    if (cap >= BIN_CAP_MIN) {
        unsigned* cursors = (unsigned*)d_ws;
        float4*   pos4    = (float4*)((unsigned*)d_ws + curWords);
        float4*   du4     = (float4*)((unsigned*)d_ws + curWords + tblWords);
        unsigned* region  = (unsigned*)d_ws + curWords + 2 * tblWords;

        prep_kernel<<<(N_NODES + 255) / 256, 256, 0, stream>>>(pos, cursors, pos4);
        bin_edges_kernel<<<A_BLOCKS, A_THREADS, 0, stream>>>(eidx, cursors,
                                                             region, cap);
        accumulate_kernel<<<NBINS, B_THREADS, 0, stream>>>(pos4, cursors, region,
                                                           cap, du, ang, du4);
        dihedral_kernel<<<N_EDGES / 256, 256, 0, stream>>>(pos4, du4, eidx, dih);
    } else {
        zero_du_kernel<<<(N_NODES * 3 + 255) / 256, 256, 0, stream>>>(du, N_NODES * 3);
        edge_scatter_kernel<<<(N_EDGES + 255) / 256, 256, 0, stream>>>(pos, eidx, du);
        angular_kernel<<<(N_NODES * 32) / 256, 256, 0, stream>>>(du, ang);
        dihedral_fallback_kernel<<<N_EDGES / 256, 256, 0, stream>>>(pos, eidx, du, dih);
    }
}

// Round 12
// 211.636 us; speedup vs baseline: 3.0431x; 1.0021x over previous
//
#include <hip/hip_runtime.h>
#include <math.h>

#define N_NODES 100000
#define N_EDGES 1600000
#define HIDDEN 128

// ---- binning geometry ------------------------------------------------------
#define NBINS      256
#define BIN_NODES  391        // 256*391 = 100096 >= 100000
#define HALF_NODES 196        // node-half split for B occupancy (196+195)
#define BIN_CAP_MAX 14336     // preferred cap; runtime-shrinks
#define BIN_CAP_MIN 13056     // below this, fall back
#define CUR_STRIDE 32         // cursors padded to 1 per 128B line
#define A_THREADS  1024
#define A_EPT      8
#define A_EPB      (A_THREADS * A_EPT)                    // 8192 edges/block
#define A_BLOCKS   ((N_EDGES + A_EPB - 1) / A_EPB)        // 196
#define B_THREADS  1024
#define NPAD       100096

// Fixed-point scale for LDS du accumulation (native ds_add_u32).
#define FP_SCALE   4194304.0f
#define FP_INV     (1.0f / 4194304.0f)

// Record layout: [26:17]=own-local node (9b), [16:0]=other node id (17b).

typedef float vfloat4 __attribute__((ext_vector_type(4)));

// ---------------------------------------------------------------------------
// Kernel Z: zero padded cursors (1 block; pos4 build moved into kernel A).
// ---------------------------------------------------------------------------
__global__ void zero_cursors_kernel(unsigned* __restrict__ cur) {
    cur[threadIdx.x * CUR_STRIDE] = 0u;
}

// ---------------------------------------------------------------------------
// Kernel A: bin edges (8 edges/thread) + build pos4 with otherwise-idle
// thread capacity (196 blocks x 1024 threads = 200704 >= N_NODES).
// ---------------------------------------------------------------------------
__global__ __launch_bounds__(A_THREADS) void bin_edges_kernel(
    const int* __restrict__ eidx,
    const float* __restrict__ pos,
    unsigned* __restrict__ cursors,
    unsigned* __restrict__ region,
    float4* __restrict__ pos4,
    int cap)
{
    __shared__ unsigned cnt[NBINS];
    __shared__ unsigned base[NBINS];
    if (threadIdx.x < NBINS) cnt[threadIdx.x] = 0u;

    // pos4 build (no sync needed with binning work; B consumes it later)
    {
        int gid = blockIdx.x * A_THREADS + threadIdx.x;
        if (gid < N_NODES)
            pos4[gid] = make_float4(pos[gid * 3 + 0], pos[gid * 3 + 1],
                                    pos[gid * 3 + 2], 0.0f);
    }
    __syncthreads();

    const int eb = blockIdx.x * A_EPB + threadIdx.x * 2;

    bool     val[A_EPT];
    unsigned r[A_EPT], c[A_EPT], br[A_EPT], bc[A_EPT], orow[A_EPT], ocol[A_EPT];

    #pragma unroll
    for (int k = 0; k < A_EPT; k += 2) {
        int e = eb + k * A_THREADS;
        bool v = (e < N_EDGES);
        val[k] = v; val[k + 1] = v;
        if (v) {
            int2 rr = *reinterpret_cast<const int2*>(eidx + e);
            int2 cc = *reinterpret_cast<const int2*>(eidx + N_EDGES + e);
            r[k] = (unsigned)rr.x; r[k + 1] = (unsigned)rr.y;
            c[k] = (unsigned)cc.x; c[k + 1] = (unsigned)cc.y;
        }
    }
    #pragma unroll
    for (int k = 0; k < A_EPT; ++k) {
        if (val[k]) {
            br[k] = r[k] / BIN_NODES;
            bc[k] = c[k] / BIN_NODES;
            orow[k] = atomicAdd(&cnt[br[k]], 1u);
            ocol[k] = atomicAdd(&cnt[bc[k]], 1u);
        }
    }
    __syncthreads();

    if (threadIdx.x < NBINS)
        base[threadIdx.x] =
            atomicAdd(&cursors[threadIdx.x * CUR_STRIDE], cnt[threadIdx.x]);
    __syncthreads();

    #pragma unroll
    for (int k = 0; k < A_EPT; ++k) {
        if (val[k]) {
            region[(size_t)br[k] * cap + base[br[k]] + orow[k]] =
                ((r[k] - br[k] * BIN_NODES) << 17) | c[k];
            region[(size_t)bc[k] * cap + base[bc[k]] + ocol[k]] =
                ((c[k] - bc[k] * BIN_NODES) << 17) | r[k];
        }
    }
}

// ---------------------------------------------------------------------------
// Kernel B: TWO blocks per bin (512 blocks -> 2 blocks/CU, 16 waves/CU).
// Each block scans the whole bin's records but accumulates only its node
// half (predicated; inactive lanes cost issue only, no LDS bank cycles).
// Writes its half of du, du4=(du.xyz,||du||^2), and angular rows.
// ---------------------------------------------------------------------------
__device__ __forceinline__ void proc_rec(unsigned rec, unsigned half,
                                         const float4* __restrict__ posLDS4,
                                         const float4* __restrict__ pos4,
                                         int* __restrict__ acc) {
    unsigned local = rec >> 17;
    unsigned h = (local >= HALF_NODES) ? 1u : 0u;   // local in [0,391)
    if (h != half) return;
    unsigned l = local - half * HALF_NODES;
    unsigned other = rec & 0x1FFFFu;
    float4 s = posLDS4[l];
    float4 p = pos4[other];
    float dx = p.x - s.x;
    float dy = p.y - s.y;
    float dz = p.z - s.z;
    float inv = 1.0f / (sqrtf(dx * dx + dy * dy + dz * dz) + 1e-8f);
    atomicAdd(&acc[l * 3 + 0], __float2int_rn(dx * inv * FP_SCALE));
    atomicAdd(&acc[l * 3 + 1], __float2int_rn(dy * inv * FP_SCALE));
    atomicAdd(&acc[l * 3 + 2], __float2int_rn(dz * inv * FP_SCALE));
}

__global__ __launch_bounds__(B_THREADS) void accumulate_kernel(
    const float4* __restrict__ pos4,
    const unsigned* __restrict__ cursors,
    const unsigned* __restrict__ region,
    int cap,
    float* __restrict__ du,
    float* __restrict__ ang,
    float4* __restrict__ du4)
{
    __shared__ int    acc[HALF_NODES * 3];       // 2352 B
    __shared__ float4 posLDS4[HALF_NODES];       // 3136 B
    const unsigned b    = blockIdx.x >> 1;
    const unsigned half = blockIdx.x & 1;
    const unsigned g0   = b * BIN_NODES + half * HALF_NODES;  // first node
    const int maxh = half ? (BIN_NODES - HALF_NODES) : HALF_NODES;
    const int rem  = (int)N_NODES - (int)g0;
    const unsigned nh = (unsigned)max(0, min(maxh, rem));

    for (int i = threadIdx.x; i < HALF_NODES * 3; i += B_THREADS) acc[i] = 0;
    for (unsigned i = threadIdx.x; i < nh; i += B_THREADS)
        posLDS4[i] = pos4[g0 + i];
    __syncthreads();

    const unsigned n = cursors[b * CUR_STRIDE];
    const unsigned* __restrict__ reg = region + (size_t)b * cap;
    const unsigned n4 = n & ~3u;

    for (unsigned i = threadIdx.x * 4; i < n4; i += B_THREADS * 4) {
        uint4 rc = *reinterpret_cast<const uint4*>(reg + i);
        proc_rec(rc.x, half, posLDS4, pos4, acc);
        proc_rec(rc.y, half, posLDS4, pos4, acc);
        proc_rec(rc.z, half, posLDS4, pos4, acc);
        proc_rec(rc.w, half, posLDS4, pos4, acc);
    }
    for (unsigned i = n4 + threadIdx.x; i < n; i += B_THREADS)
        proc_rec(reg[i], half, posLDS4, pos4, acc);
    __syncthreads();

    for (unsigned i = threadIdx.x; i < nh * 3; i += B_THREADS)
        du[(size_t)g0 * 3 + i] = (float)acc[i] * FP_INV;

    for (unsigned i = threadIdx.x; i < nh; i += B_THREADS) {
        float x = (float)acc[i * 3 + 0] * FP_INV;
        float y = (float)acc[i * 3 + 1] * FP_INV;
        float z = (float)acc[i * 3 + 2] * FP_INV;
        du4[g0 + i] = make_float4(x, y, z, x * x + y * y + z * z);
    }

    for (unsigned j = threadIdx.x; j < nh * 32; j += B_THREADS) {
        unsigned node = j >> 5, c4 = j & 31;
        float x = (float)acc[node * 3 + 0] * FP_INV;
        float y = (float)acc[node * 3 + 1] * FP_INV;
        float z = (float)acc[node * 3 + 2] * FP_INV;
        float a = x * x + y * y + z * z;
        vfloat4 v4 = {a, a, a, a};
        __builtin_nontemporal_store(v4,
            reinterpret_cast<vfloat4*>(ang + (size_t)(g0 + node) * HIDDEN) + c4);
    }
}

// ---------------------------------------------------------------------------
// Kernel C: dihedral via pos4/du4 vector gathers (unchanged from R11).
// w_ij . w_ji = v_i.v_j - (v_i.u)(v_j.u)(2 - u.u)  [exact algebra]
// ---------------------------------------------------------------------------
__global__ __launch_bounds__(256) void dihedral_kernel(
    const float4* __restrict__ pos4,
    const float4* __restrict__ du4,
    const int* __restrict__ eidx,
    float* __restrict__ dih)
{
    __shared__ float vals[256];
    const int e0 = blockIdx.x * 256;
    const int e  = e0 + threadIdx.x;

    {
        int r = eidx[e];
        int c = eidx[N_EDGES + e];
        float4 pr = pos4[r];
        float4 pc = pos4[c];
        float4 vi = du4[r];
        float4 vj = du4[c];

        float dx = pc.x - pr.x, dy = pc.y - pr.y, dz = pc.z - pr.z;
        float inv = 1.0f / (sqrtf(dx * dx + dy * dy + dz * dz) + 1e-8f);
        float ux = dx * inv, uy = dy * inv, uz = dz * inv;

        float a  = vi.x * ux + vi.y * uy + vi.z * uz;
        float b  = vj.x * ux + vj.y * uy + vj.z * uz;
        float vv = vi.x * vj.x + vi.y * vj.y + vi.z * vj.z;
        float uu = ux * ux + uy * uy + uz * uz;

        vals[threadIdx.x] = vv - a * b * (2.0f - uu);
    }
    __syncthreads();

    vfloat4* out = reinterpret_cast<vfloat4*>(dih + (size_t)e0 * HIDDEN);
    #pragma unroll
    for (int it = 0; it < 32; ++it) {
        int i = it * 256 + threadIdx.x;
        float v = vals[i >> 5];
        vfloat4 v4 = {v, v, v, v};
        __builtin_nontemporal_store(v4, out + i);
    }
}

// ---------------------------------------------------------------------------
// Fallback path (ws too small): direct native-atomic scatter + fused dihedral.
// ---------------------------------------------------------------------------
__global__ void zero_du_kernel(float* __restrict__ du, int n) {
    int i = blockIdx.x * blockDim.x + threadIdx.x;
    if (i < n) du[i] = 0.0f;
}

__global__ void edge_scatter_kernel(const float* __restrict__ pos,
                                    const int* __restrict__ eidx,
                                    float* __restrict__ du) {
    int e = blockIdx.x * blockDim.x + threadIdx.x;
    if (e >= N_EDGES) return;
    int r = eidx[e];
    int c = eidx[N_EDGES + e];
    float dx = pos[c * 3 + 0] - pos[r * 3 + 0];
    float dy = pos[c * 3 + 1] - pos[r * 3 + 1];
    float dz = pos[c * 3 + 2] - pos[r * 3 + 2];
    float inv = 1.0f / (sqrtf(dx * dx + dy * dy + dz * dz) + 1e-8f);
    float ux = dx * inv, uy = dy * inv, uz = dz * inv;
    unsafeAtomicAdd(&du[r * 3 + 0],  ux);
    unsafeAtomicAdd(&du[r * 3 + 1],  uy);
    unsafeAtomicAdd(&du[r * 3 + 2],  uz);
    unsafeAtomicAdd(&du[c * 3 + 0], -ux);
    unsafeAtomicAdd(&du[c * 3 + 1], -uy);
    unsafeAtomicAdd(&du[c * 3 + 2], -uz);
}

__global__ void angular_kernel(const float* __restrict__ du,
                               float* __restrict__ ang) {
    int gid = blockIdx.x * blockDim.x + threadIdx.x;
    int node = gid >> 5;
    int c4   = gid & 31;
    float x = du[node * 3 + 0];
    float y = du[node * 3 + 1];
    float z = du[node * 3 + 2];
    float a = x * x + y * y + z * z;
    vfloat4 v4 = {a, a, a, a};
    __builtin_nontemporal_store(v4,
        reinterpret_cast<vfloat4*>(ang + (size_t)node * HIDDEN) + c4);
}

__global__ __launch_bounds__(256) void dihedral_fallback_kernel(
    const float* __restrict__ pos,
    const int* __restrict__ eidx,
    const float* __restrict__ du,
    float* __restrict__ dih)
{
    __shared__ float vals[256];
    const int e0 = blockIdx.x * 256;
    const int e  = e0 + threadIdx.x;
    {
        int r = eidx[e];
        int c = eidx[N_EDGES + e];
        float dx = pos[c * 3 + 0] - pos[r * 3 + 0];
        float dy = pos[c * 3 + 1] - pos[r * 3 + 1];
        float dz = pos[c * 3 + 2] - pos[r * 3 + 2];
        float inv = 1.0f / (sqrtf(dx * dx + dy * dy + dz * dz) + 1e-8f);
        float ux = dx * inv, uy = dy * inv, uz = dz * inv;
        float vix = du[r * 3 + 0], viy = du[r * 3 + 1], viz = du[r * 3 + 2];
        float vjx = du[c * 3 + 0], vjy = du[c * 3 + 1], vjz = du[c * 3 + 2];
        float dvi = vix * ux + viy * uy + viz * uz;
        float dvj = -(vjx * ux + vjy * uy + vjz * uz);
        float wix = vix - dvi * ux, wiy = viy - dvi * uy, wiz = viz - dvi * uz;
        float wjx = vjx + dvj * ux, wjy = vjy + dvj * uy, wjz = vjz + dvj * uz;
        vals[threadIdx.x] = wix * wjx + wiy * wjy + wiz * wjz;
    }
    __syncthreads();
    vfloat4* out = reinterpret_cast<vfloat4*>(dih + (size_t)e0 * HIDDEN);
    #pragma unroll
    for (int it = 0; it < 32; ++it) {
        int i = it * 256 + threadIdx.x;
        float v = vals[i >> 5];
        vfloat4 v4 = {v, v, v, v};
        __builtin_nontemporal_store(v4, out + i);
    }
}

// ---------------------------------------------------------------------------
extern "C" void kernel_launch(void* const* d_in, const int* in_sizes, int n_in,
                              void* d_out, int out_size, void* d_ws, size_t ws_size,
                              hipStream_t stream) {
    const float* pos  = (const float*)d_in[0];
    const int*   eidx = (const int*)d_in[1];

    float* out = (float*)d_out;
    float* ang = out;                                         // (N, 128)
    float* dih = out + (size_t)N_NODES * HIDDEN;              // (E, 128)
    float* du  = dih + (size_t)N_EDGES * HIDDEN;              // (N, 3)

    // ws layout: cursors | pos4 | du4 | region (runtime-capped bins)
    const size_t curWords  = (size_t)NBINS * CUR_STRIDE;   // 8192
    const size_t tblWords  = (size_t)NPAD * 4;             // 400384 each
    const size_t wsWords   = ws_size / 4;

    int cap = 0;
    if (wsWords > curWords + 2 * tblWords) {
        size_t avail = (wsWords - curWords - 2 * tblWords) / NBINS;
        avail &= ~(size_t)255;
        cap = (int)(avail < BIN_CAP_MAX ? avail : BIN_CAP_MAX);
    }

    if (cap >= BIN_CAP_MIN) {
        unsigned* cursors = (unsigned*)d_ws;
        float4*   pos4    = (float4*)((unsigned*)d_ws + curWords);
        float4*   du4     = (float4*)((unsigned*)d_ws + curWords + tblWords);
        unsigned* region  = (unsigned*)d_ws + curWords + 2 * tblWords;

        zero_cursors_kernel<<<1, NBINS, 0, stream>>>(cursors);
        bin_edges_kernel<<<A_BLOCKS, A_THREADS, 0, stream>>>(eidx, pos, cursors,
                                                             region, pos4, cap);
        accumulate_kernel<<<NBINS * 2, B_THREADS, 0, stream>>>(pos4, cursors,
                                                               region, cap,
                                                               du, ang, du4);
        dihedral_kernel<<<N_EDGES / 256, 256, 0, stream>>>(pos4, du4, eidx, dih);
    } else {
        zero_du_kernel<<<(N_NODES * 3 + 255) / 256, 256, 0, stream>>>(du, N_NODES * 3);
        edge_scatter_kernel<<<(N_EDGES + 255) / 256, 256, 0, stream>>>(pos, eidx, du);
        angular_kernel<<<(N_NODES * 32) / 256, 256, 0, stream>>>(du, ang);
        dihedral_fallback_kernel<<<N_EDGES / 256, 256, 0, stream>>>(pos, eidx, du, dih);
    }
}